// Round 11
// baseline (414.996 us; speedup 1.0000x reference)
//
#include <hip/hip_runtime.h>
#include <hip/hip_bf16.h>
#include <stdint.h>

#define NE 8
#define T_TOK 4096
#define H_DIM 1024
#define I_DIM 4096
#define CAP 4096
#define RB256 40  // max 256-row blocks: 8192/256 + 8
#define RB128 72  // max 128-row blocks: 8192/128 + 8

typedef __attribute__((ext_vector_type(8))) short bf16x8;
typedef __attribute__((ext_vector_type(4))) float f32x4;
typedef __attribute__((ext_vector_type(8))) unsigned short u16x8;

__device__ __forceinline__ unsigned short f2bf(float f) {
  __hip_bfloat16 h = __float2bfloat16(f);
  return *reinterpret_cast<unsigned short*>(&h);
}

__device__ __forceinline__ void lds_load16(const void* g, void* l) {
  __builtin_amdgcn_global_load_lds((__attribute__((address_space(1))) void*)g,
                                   (__attribute__((address_space(3))) void*)l,
                                   16, 0, 0);
}

// swizzled LDS fragment read: tile layout [rows][64 bf16] (128B rows, 8x16B
// chunks); content chunk cc of row lives at physical chunk cc ^ (row&7)
__device__ __forceinline__ const bf16x8* lds_frag(const char* base, int row,
                                                  int cc) {
  return (const bf16x8*)(base + row * 128 + ((cc ^ (row & 7)) << 4));
}

// bijective XCD swizzle (nwg % 8 == 0): each XCD owns a contiguous logical chunk
__device__ __forceinline__ int xcd_swz(int bid, int nwg) {
  return (bid & 7) * (nwg >> 3) + (bid >> 3);
}

// slot layout: per-expert regions padded to 256 rows, concatenated.
// 256-block lookup (ffn1): flat block g -> (e, mb); rowbase = 256*g exactly.
__device__ __forceinline__ bool rb_lookup256(const int* counts, int g,
                                             int* e_out, int* mb_out,
                                             int* cnt_out) {
  int acc = 0;
#pragma unroll
  for (int i = 0; i < NE; ++i) {
    int c = counts[i];
    int rb = (c + 255) >> 8;
    if (g < acc + rb) {
      *e_out = i;
      *mb_out = g - acc;
      *cnt_out = c;
      return true;
    }
    acc += rb;
  }
  return false;
}

// 128-block lookup against the 256-padded layout (ffn2)
__device__ __forceinline__ bool rb_lookup128(const int* counts, int g,
                                             int* e_out, int* rowbase,
                                             int* cnt_out) {
  int acc = 0, base = 0;
#pragma unroll
  for (int i = 0; i < NE; ++i) {
    int c = counts[i];
    int rb = (c + 127) >> 7;
    if (g < acc + rb) {
      *e_out = i;
      *rowbase = base + (g - acc) * 128;
      *cnt_out = c;
      return true;
    }
    acc += rb;
    base += (c + 255) & ~255;
  }
  return false;
}

// ---------------- router: 1 wave per token ----------------
__global__ void router_kernel(const float* __restrict__ x,
                              const float* __restrict__ rw,
                              int* __restrict__ counts,
                              int* __restrict__ perm,
                              int* __restrict__ se,
                              float* __restrict__ wtok) {
  const int t = blockIdx.x;
  const int lane = threadIdx.x;  // 64 threads
  float acc[NE];
#pragma unroll
  for (int e = 0; e < NE; ++e) acc[e] = 0.f;
  const float* xr = x + (size_t)t * H_DIM;
#pragma unroll
  for (int it = 0; it < H_DIM / 64; ++it) {
    int d = it * 64 + lane;
    float xv = xr[d];
#pragma unroll
    for (int e = 0; e < NE; ++e) acc[e] += xv * rw[e * H_DIM + d];
  }
#pragma unroll
  for (int e = 0; e < NE; ++e) {
#pragma unroll
    for (int off = 32; off > 0; off >>= 1) acc[e] += __shfl_xor(acc[e], off);
  }
  if (lane == 0) {
    int i0 = 0;
#pragma unroll
    for (int e = 1; e < NE; ++e)
      if (acc[e] > acc[i0]) i0 = e;
    int i1 = (i0 == 0) ? 1 : 0;
#pragma unroll
    for (int e = 0; e < NE; ++e)
      if (e != i0 && acc[e] > acc[i1]) i1 = e;
    float la = acc[i0], lb = acc[i1];
    float r = expf(lb - la);          // <= 1
    float wa = 1.f / (1.f + r);       // normalized top-2 softmax weights
    float wb = 1.f - wa;
    int p0 = atomicAdd(&counts[i0], 1);
    perm[i0 * CAP + p0] = t;
    se[2 * t + 0] = (i0 << 20) | p0;
    wtok[2 * t + 0] = wa;
    int p1 = atomicAdd(&counts[i1], 1);
    perm[i1 * CAP + p1] = t;
    se[2 * t + 1] = (i1 << 20) | p1;
    wtok[2 * t + 1] = wb;
  }
}

// ---------------- x -> bf16 ----------------
__global__ void convert_x_kernel(const float* __restrict__ x,
                                 unsigned short* __restrict__ xb) {
  int i = blockIdx.x * blockDim.x + threadIdx.x;  // one float4 each
  float4 v = reinterpret_cast<const float4*>(x)[i];
  ushort4 o;
  o.x = f2bf(v.x); o.y = f2bf(v.y); o.z = f2bf(v.z); o.w = f2bf(v.w);
  reinterpret_cast<ushort4*>(xb)[i] = o;
}

// ---------------- transpose + convert: src [E][R][C] f32 -> dst [E][C][R] bf16
__global__ void __launch_bounds__(256) transpose_conv_kernel(
    const float* __restrict__ src, unsigned short* __restrict__ dst,
    int R, int C) {
  __shared__ float tile[64][65];
  const int e = blockIdx.z;
  const int c0 = blockIdx.x * 64, r0 = blockIdx.y * 64;
  const float* s = src + (size_t)e * R * C;
  unsigned short* d = dst + (size_t)e * R * C;
  const int tid = threadIdx.x;
  const int lr = tid >> 4, lc = (tid & 15) << 2;
#pragma unroll
  for (int j = 0; j < 4; ++j) {
    float4 v = *reinterpret_cast<const float4*>(
        &s[(size_t)(r0 + j * 16 + lr) * C + c0 + lc]);
    tile[j * 16 + lr][lc + 0] = v.x;
    tile[j * 16 + lr][lc + 1] = v.y;
    tile[j * 16 + lr][lc + 2] = v.z;
    tile[j * 16 + lr][lc + 3] = v.w;
  }
  __syncthreads();
  const int oc = tid >> 3, orr = (tid & 7) << 3;
#pragma unroll
  for (int j = 0; j < 2; ++j) {
    int c = j * 32 + oc;
    u16x8 o;
#pragma unroll
    for (int k = 0; k < 8; ++k) o[k] = f2bf(tile[orr + k][c]);
    *reinterpret_cast<u16x8*>(&d[(size_t)(c0 + c) * R + r0 + orr]) = o;
  }
}

// ---------------- FFN1: inter = gelu(X[perm] @ w_in + b_in), bf16 out --------
// 8-phase-style fine interleave: 256x256 tile, BK=64, 512 thr (8 waves 2Mx4N,
// 128x64/wave). Per K-tile: 4 phases {stage 1 half-tile of NEXT K-tile into
// the buffer freed at the previous __syncthreads ; ds_read quadrant frags ;
// setprio(1) 16 MFMA setprio(0) ; raw s_barrier}, then ONE __syncthreads
// (drain+fence) per K-tile. Race-free: stores to a buffer only issue after
// the barrier ending its reads; drained before its next reads.
// T2 chunk-swizzle. Grid 16nb * RB256 = 640 (XCD-swizzled, nb-major).
__global__ void __launch_bounds__(512, 2) ffn1_kernel(
    const unsigned short* __restrict__ xb,
    const unsigned short* __restrict__ win_t,  // [E][I][H]
    const float* __restrict__ b_in,            // [E][I]
    const int* __restrict__ counts,
    const int* __restrict__ perm,
    unsigned short* __restrict__ inter) {
  const int logical = xcd_swz(blockIdx.x, 16 * RB256);
  const int nb = logical / RB256;  // consecutive logicals share B panel
  const int g = logical % RB256;
  int e, mb, cnt;
  if (!rb_lookup256(counts, g, &e, &mb, &cnt)) return;

  extern __shared__ char smem[];  // [2][ A 32KB | B 32KB ] = 128KB

  const int tid = threadIdx.x;
  int tokr[4];  // [h*2+it] -> tile row h*128 + it*64 + (tid>>3)
#pragma unroll
  for (int h = 0; h < 2; ++h)
#pragma unroll
    for (int it = 0; it < 2; ++it) {
      int r = h * 128 + it * 64 + (tid >> 3);
      tokr[h * 2 + it] = perm[e * CAP + min(mb * 256 + r, cnt - 1)];
    }

  const int wave = tid >> 6, lane = tid & 63;
  const int wr = wave >> 2, wn = wave & 3;  // 2M x 4N, per-wave 128x64
  const int l16 = lane & 15, l4 = lane >> 4;
  const unsigned short* Bbase =
      win_t + (size_t)e * I_DIM * H_DIM + (size_t)(nb * 256) * H_DIM;

  // stage one half-tile (hs: 0=A0,1=B0,2=A1,3=B1) of K-tile kt into buffer b.
  // 2 gload_lds/thread; source chunk pre-swizzled (T2 both-sides), dest linear.
  auto stage_half = [&](int b, int kt, int hs) {
    const int h = hs >> 1, isB = hs & 1;
#pragma unroll
    for (int it = 0; it < 2; ++it) {
      int id = it * 512 + tid;          // 0..1023
      int rl = id >> 3;                 // 0..127
      int cs = (id & 7) ^ (rl & 7);     // (row&7)==(rl&7) since 128%8==0
      char* dst = smem + b * 65536 + isB * 32768 + h * 16384 + id * 16;
      if (!isB)
        lds_load16(xb + (size_t)tokr[h * 2 + it] * H_DIM + kt * 64 + cs * 8, dst);
      else
        lds_load16(Bbase + (size_t)(h * 128 + rl) * H_DIM + kt * 64 + cs * 8, dst);
    }
  };

  f32x4 acc[8][4] = {};

  // quadrant compute: (mh,nh) selects 64 rows x 32 cols of the wave's 128x64
  auto do_quad = [&](int b, int mh, int nh, bf16x8* af, bool loadA) {
    const char* Ab = smem + b * 65536;
    const char* Bb = Ab + 32768;
    if (loadA) {
#pragma unroll
      for (int mf = 0; mf < 4; ++mf)
#pragma unroll
        for (int kk = 0; kk < 2; ++kk)
          af[mf * 2 + kk] =
              *lds_frag(Ab, wr * 128 + mh * 64 + mf * 16 + l16, kk * 4 + l4);
    }
    bf16x8 bv[4];
#pragma unroll
    for (int nf = 0; nf < 2; ++nf)
#pragma unroll
      for (int kk = 0; kk < 2; ++kk)
        bv[nf * 2 + kk] =
            *lds_frag(Bb, wn * 64 + nh * 32 + nf * 16 + l16, kk * 4 + l4);
    __builtin_amdgcn_s_setprio(1);
#pragma unroll
    for (int mf = 0; mf < 4; ++mf)
#pragma unroll
      for (int nf = 0; nf < 2; ++nf)
#pragma unroll
        for (int kk = 0; kk < 2; ++kk)
          acc[mh * 4 + mf][nh * 2 + nf] = __builtin_amdgcn_mfma_f32_16x16x32_bf16(
              af[mf * 2 + kk], bv[nf * 2 + kk], acc[mh * 4 + mf][nh * 2 + nf],
              0, 0, 0);
    __builtin_amdgcn_s_setprio(0);
  };

  // prologue: stage tile 0 -> buf0, drain
#pragma unroll
  for (int hs = 0; hs < 4; ++hs) stage_half(0, 0, hs);
  __syncthreads();

  const int NT = H_DIM / 64;  // 16 K-tiles
  for (int tt = 0; tt < NT; ++tt) {
    const int b = tt & 1;
    const int nxt = tt + 1;
    bf16x8 af[8];
    if (nxt < NT) stage_half(b ^ 1, nxt, 0);
    do_quad(b, 0, 0, af, true);
    __builtin_amdgcn_s_barrier();
    if (nxt < NT) stage_half(b ^ 1, nxt, 1);
    do_quad(b, 0, 1, af, false);
    __builtin_amdgcn_s_barrier();
    if (nxt < NT) stage_half(b ^ 1, nxt, 2);
    do_quad(b, 1, 0, af, true);
    __builtin_amdgcn_s_barrier();
    if (nxt < NT) stage_half(b ^ 1, nxt, 3);
    do_quad(b, 1, 1, af, false);
    __syncthreads();  // drains next-tile stage loads + fences buffer swap
  }

  // ---- epilogue: GELU, coalesce via per-wave 16KB LDS slice ----
  const size_t rowbase = (size_t)g * 256;
  unsigned short* slice = (unsigned short*)(smem + wave * 16384);
#pragma unroll
  for (int n = 0; n < 4; ++n) {
    float bias = b_in[e * I_DIM + nb * 256 + wn * 64 + n * 16 + l16];
#pragma unroll
    for (int m = 0; m < 8; ++m) {
#pragma unroll
      for (int j = 0; j < 4; ++j) {
        float v = acc[m][n][j] + bias;
        // tanh-form GELU: v * sigmoid(1.59577(v + 0.044715 v^3)); |err| <~1e-3
        float t = __expf(-1.5957691216057308f * v - 0.07135481627f * v * v * v);
        float gg = v / (1.f + t);
        slice[(m * 16 + l4 * 4 + j) * 64 + n * 16 + l16] = f2bf(gg);
      }
    }
  }
  __syncthreads();  // slice writes visible before cross-lane readback
#pragma unroll
  for (int it = 0; it < 16; ++it) {
    int row = it * 8 + (lane >> 3);        // 0..127
    int colb = (lane & 7) * 8;             // 8 bf16 = 16B
    u16x8 v = *(const u16x8*)&slice[row * 64 + colb];
    *(u16x8*)&inter[(rowbase + wr * 128 + row) * (size_t)I_DIM + nb * 256 +
                    wn * 64 + colb] = v;
  }
}

// ---------------- FFN2: y[slot] = inter @ w_out + b_out (dense, no atomics) --
// r10's proven m97 2ph kernel; only the slot lookup changed (256-padded base).
__global__ void __launch_bounds__(256, 3) ffn2_kernel(
    const unsigned short* __restrict__ inter,
    const unsigned short* __restrict__ wout_t,  // [E][H][I]
    const float* __restrict__ b_out,            // [E][H]
    const int* __restrict__ counts,
    float* __restrict__ y) {                    // [slot][H]
  const int logical = xcd_swz(blockIdx.x, RB128 * 8);
  const int g = logical >> 3;      // consecutive logicals share A panel
  const int nb = logical & 7;
  int e, rowbase_i, cnt;
  if (!rb_lookup128(counts, g, &e, &rowbase_i, &cnt)) return;
  const size_t rowbase = (size_t)rowbase_i;

  __shared__ char smem[32768];  // A 16KB | B 16KB

  const int tid = threadIdx.x;
  const int wave = tid >> 6, lane = tid & 63;
  const int wr = wave >> 1, wn = wave & 1;  // 2M x 2N
  const int l16 = lane & 15, l4 = lane >> 4;
  const unsigned short* Bbase =
      wout_t + (size_t)e * H_DIM * I_DIM + (size_t)(nb * 128) * I_DIM;

  f32x4 acc[4][4] = {};

  const int NK = I_DIM / 64;  // 64
  for (int kt = 0; kt < NK; ++kt) {
    __syncthreads();
#pragma unroll
    for (int it = 0; it < 4; ++it) {
      int id = it * 256 + tid;
      int r = id >> 3;
      int cs = (id & 7) ^ (r & 7);
      lds_load16(inter + (rowbase + r) * (size_t)I_DIM + kt * 64 + cs * 8,
                 smem + id * 16);
      lds_load16(Bbase + (size_t)r * I_DIM + kt * 64 + cs * 8,
                 smem + 16384 + id * 16);
    }
    __syncthreads();
#pragma unroll
    for (int kk = 0; kk < 2; ++kk) {
      bf16x8 af[4], bv[4];
#pragma unroll
      for (int m = 0; m < 4; ++m)
        af[m] = *lds_frag(smem, wr * 64 + m * 16 + l16, kk * 4 + l4);
#pragma unroll
      for (int n = 0; n < 4; ++n)
        bv[n] = *lds_frag(smem + 16384, wn * 64 + n * 16 + l16, kk * 4 + l4);
#pragma unroll
      for (int m = 0; m < 4; ++m)
#pragma unroll
        for (int n = 0; n < 4; ++n)
          acc[m][n] =
              __builtin_amdgcn_mfma_f32_16x16x32_bf16(af[m], bv[n], acc[m][n], 0, 0, 0);
    }
  }

  // ---- epilogue: two 32-row passes through per-wave 8KB LDS slice ----
  __syncthreads();
  float* slice = (float*)(smem + wave * 8192);
  float bias[4];
#pragma unroll
  for (int n = 0; n < 4; ++n)
    bias[n] = b_out[e * H_DIM + nb * 128 + wn * 64 + n * 16 + l16];
#pragma unroll
  for (int p = 0; p < 2; ++p) {
#pragma unroll
    for (int mm = 0; mm < 2; ++mm) {
      int m = p * 2 + mm;
#pragma unroll
      for (int n = 0; n < 4; ++n) {
#pragma unroll
        for (int j = 0; j < 4; ++j) {
          slice[(mm * 16 + l4 * 4 + j) * 64 + n * 16 + l16] =
              acc[m][n][j] + bias[n];
        }
      }
    }
    __syncthreads();  // slice writes visible before cross-lane readback
#pragma unroll
    for (int it = 0; it < 8; ++it) {
      int row = it * 4 + (lane >> 4);      // 0..31
      int col = (lane & 15) * 4;           // 4 floats = 16B
      float4 v = *(const float4*)&slice[row * 64 + col];
      *(float4*)&y[(rowbase + wr * 64 + p * 32 + row) * (size_t)H_DIM +
                   nb * 128 + wn * 64 + col] = v;
    }
    __syncthreads();  // readback done before next pass overwrites slice
  }
}

// ---------------- combine: out[t] = w0*y[slot0] + w1*y[slot1] ---------------
__global__ void __launch_bounds__(256) combine_kernel(
    const float* __restrict__ y, const int* __restrict__ counts,
    const int* __restrict__ se, const float* __restrict__ wtok,
    float* __restrict__ out) {
  const int t = blockIdx.x;
  int poff[NE];
  int run = 0;
#pragma unroll
  for (int e = 0; e < NE; ++e) {
    poff[e] = run;
    run += (counts[e] + 255) & ~255;  // must match 256-row padding
  }
  int c0 = se[2 * t], c1 = se[2 * t + 1];
  float w0 = wtok[2 * t], w1 = wtok[2 * t + 1];
  const float* y0 = y + (size_t)(poff[c0 >> 20] + (c0 & 0xFFFFF)) * H_DIM;
  const float* y1 = y + (size_t)(poff[c1 >> 20] + (c1 & 0xFFFFF)) * H_DIM;
  int h = threadIdx.x * 4;
  float4 a = *reinterpret_cast<const float4*>(y0 + h);
  float4 b = *reinterpret_cast<const float4*>(y1 + h);
  float4 o;
  o.x = w0 * a.x + w1 * b.x;
  o.y = w0 * a.y + w1 * b.y;
  o.z = w0 * a.z + w1 * b.z;
  o.w = w0 * a.w + w1 * b.w;
  *reinterpret_cast<float4*>(out + (size_t)t * H_DIM + h) = o;
}

extern "C" void kernel_launch(void* const* d_in, const int* in_sizes, int n_in,
                              void* d_out, int out_size, void* d_ws, size_t ws_size,
                              hipStream_t stream) {
  const float* x     = (const float*)d_in[0];
  const float* rw    = (const float*)d_in[1];
  const float* w_in  = (const float*)d_in[2];
  const float* b_in  = (const float*)d_in[3];
  const float* w_out = (const float*)d_in[4];
  const float* b_out = (const float*)d_in[5];
  float* out = (float*)d_out;

  char* ws = (char*)d_ws;
  size_t off = 0;
  auto alloc = [&](size_t bytes) {
    char* p = ws + off;
    off = (off + bytes + 255) & ~(size_t)255;
    return p;
  };
  int* counts            = (int*)alloc(NE * 4);
  int* perm              = (int*)alloc((size_t)NE * CAP * 4);
  int* se                = (int*)alloc((size_t)T_TOK * 2 * 4);
  float* wtok            = (float*)alloc((size_t)T_TOK * 2 * 4);
  unsigned short* xb     = (unsigned short*)alloc((size_t)T_TOK * H_DIM * 2);
  unsigned short* win_t  = (unsigned short*)alloc((size_t)NE * H_DIM * I_DIM * 2);
  unsigned short* wout_t = (unsigned short*)alloc((size_t)NE * H_DIM * I_DIM * 2);
  unsigned short* inter  = (unsigned short*)alloc((size_t)(T_TOK * 2 + NE * 256) * I_DIM * 2);
  // y overlays ONLY win_t (dead after ffn1; rewritten by transpose before the
  // next ffn1): need <= 10240*1024*4 = 40MB <= 64MB
  float* y = (float*)win_t;
  if (off > ws_size) return;  // ws too small -> visible correctness failure

  hipMemsetAsync(counts, 0, NE * sizeof(int), stream);
  hipFuncSetAttribute((const void*)ffn1_kernel,
                      hipFuncAttributeMaxDynamicSharedMemorySize, 131072);

  router_kernel<<<T_TOK, 64, 0, stream>>>(x, rw, counts, perm, se, wtok);
  convert_x_kernel<<<(T_TOK * H_DIM / 4) / 256, 256, 0, stream>>>(x, xb);
  transpose_conv_kernel<<<dim3(I_DIM / 64, H_DIM / 64, NE), 256, 0, stream>>>(
      w_in, win_t, H_DIM, I_DIM);
  transpose_conv_kernel<<<dim3(H_DIM / 64, I_DIM / 64, NE), 256, 0, stream>>>(
      w_out, wout_t, I_DIM, H_DIM);
  ffn1_kernel<<<16 * RB256, 512, 131072, stream>>>(xb, win_t, b_in, counts,
                                                   perm, inter);
  ffn2_kernel<<<RB128 * 8, 256, 0, stream>>>(inter, wout_t, b_out, counts, y);
  combine_kernel<<<T_TOK, 256, 0, stream>>>(y, counts, se, wtok, out);
}

// Round 12
// 381.793 us; speedup vs baseline: 1.0870x; 1.0870x over previous
//
#include <hip/hip_runtime.h>
#include <hip/hip_bf16.h>
#include <stdint.h>

#define NE 8
#define T_TOK 4096
#define H_DIM 1024
#define I_DIM 4096
#define CAP 4096
#define RB128 72  // max total 128-row blocks: 8192/128 + 8 = 72

typedef __attribute__((ext_vector_type(8))) short bf16x8;
typedef __attribute__((ext_vector_type(4))) float f32x4;
typedef __attribute__((ext_vector_type(8))) unsigned short u16x8;

__device__ __forceinline__ unsigned short f2bf(float f) {
  __hip_bfloat16 h = __float2bfloat16(f);
  return *reinterpret_cast<unsigned short*>(&h);
}

__device__ __forceinline__ void lds_load16(const void* g, void* l) {
  __builtin_amdgcn_global_load_lds((__attribute__((address_space(1))) void*)g,
                                   (__attribute__((address_space(3))) void*)l,
                                   16, 0, 0);
}

// swizzled LDS fragment read: tile layout [rows][64 bf16] (128B rows, 8x16B
// chunks); content chunk cc of row lives at physical chunk cc ^ (row&7)
__device__ __forceinline__ const bf16x8* lds_frag(const char* base, int row,
                                                  int cc) {
  return (const bf16x8*)(base + row * 128 + ((cc ^ (row & 7)) << 4));
}

// bijective XCD swizzle (nwg % 8 == 0): each XCD owns a contiguous logical chunk
__device__ __forceinline__ int xcd_swz(int bid, int nwg) {
  return (bid & 7) * (nwg >> 3) + (bid >> 3);
}

// map flat 128-row block g -> (expert e, local block mb); rowbase is 128*g
__device__ __forceinline__ bool rb_lookup(const int* counts, int g, int* e_out,
                                          int* mb_out, int* cnt_out) {
  int acc = 0;
#pragma unroll
  for (int i = 0; i < NE; ++i) {
    int c = counts[i];
    int rb = (c + 127) >> 7;
    if (g < acc + rb) {
      *e_out = i;
      *mb_out = g - acc;
      *cnt_out = c;
      return true;
    }
    acc += rb;
  }
  return false;
}

// ---------------- fused router + x->bf16 convert: 1 block per token ---------
__global__ void __launch_bounds__(256) router_convert_kernel(
    const float* __restrict__ x, const float* __restrict__ rw,
    int* __restrict__ counts, int* __restrict__ perm, int* __restrict__ se,
    float* __restrict__ wtok, unsigned short* __restrict__ xb) {
  const int t = blockIdx.x;
  const int tid = threadIdx.x;
  __shared__ float red[4][NE];

  // one float4 of the token row per thread: convert+store bf16, partial dots
  float4 v = reinterpret_cast<const float4*>(x + (size_t)t * H_DIM)[tid];
  ushort4 o;
  o.x = f2bf(v.x); o.y = f2bf(v.y); o.z = f2bf(v.z); o.w = f2bf(v.w);
  reinterpret_cast<ushort4*>(xb + (size_t)t * H_DIM)[tid] = o;

  float part[NE];
#pragma unroll
  for (int e = 0; e < NE; ++e) {
    float4 w = reinterpret_cast<const float4*>(rw + (size_t)e * H_DIM)[tid];
    part[e] = v.x * w.x + v.y * w.y + v.z * w.z + v.w * w.w;
  }
  const int wave = tid >> 6, lane = tid & 63;
#pragma unroll
  for (int e = 0; e < NE; ++e) {
#pragma unroll
    for (int off = 32; off > 0; off >>= 1) part[e] += __shfl_xor(part[e], off);
  }
  if (lane == 0) {
#pragma unroll
    for (int e = 0; e < NE; ++e) red[wave][e] = part[e];
  }
  __syncthreads();
  if (tid == 0) {
    float acc[NE];
#pragma unroll
    for (int e = 0; e < NE; ++e)
      acc[e] = red[0][e] + red[1][e] + red[2][e] + red[3][e];
    int i0 = 0;
#pragma unroll
    for (int e = 1; e < NE; ++e)
      if (acc[e] > acc[i0]) i0 = e;
    int i1 = (i0 == 0) ? 1 : 0;
#pragma unroll
    for (int e = 0; e < NE; ++e)
      if (e != i0 && acc[e] > acc[i1]) i1 = e;
    float la = acc[i0], lb = acc[i1];
    float r = expf(lb - la);          // <= 1
    float wa = 1.f / (1.f + r);       // normalized top-2 softmax weights
    float wb = 1.f - wa;
    int p0 = atomicAdd(&counts[i0], 1);
    perm[i0 * CAP + p0] = t;
    se[2 * t + 0] = (i0 << 20) | p0;
    wtok[2 * t + 0] = wa;
    int p1 = atomicAdd(&counts[i1], 1);
    perm[i1 * CAP + p1] = t;
    se[2 * t + 1] = (i1 << 20) | p1;
    wtok[2 * t + 1] = wb;
  }
}

// ---------------- dual transpose + convert (one launch for both weights) ----
// z<8: w_in [e][1024][4096] -> win_t [e][4096][1024]
// z>=8: w_out[e][4096][1024] -> wout_t[e][1024][4096]
__global__ void __launch_bounds__(256) transpose_conv2_kernel(
    const float* __restrict__ w_in, const float* __restrict__ w_out,
    unsigned short* __restrict__ win_t, unsigned short* __restrict__ wout_t) {
  __shared__ float tile[64][65];
  const int z = blockIdx.z;
  const bool second = z >= 8;
  const int e = z & 7;
  const float* src = second ? w_out : w_in;
  unsigned short* dstp = second ? wout_t : win_t;
  const int R = second ? I_DIM : H_DIM;
  const int C = second ? H_DIM : I_DIM;
  // grid (64,16): w_in needs (C/64=64, R/64=16); w_out swaps the roles
  const int c0 = (second ? blockIdx.y : blockIdx.x) * 64;
  const int r0 = (second ? blockIdx.x : blockIdx.y) * 64;
  const float* s = src + (size_t)e * R * C;
  unsigned short* d = dstp + (size_t)e * R * C;
  const int tid = threadIdx.x;
  const int lr = tid >> 4, lc = (tid & 15) << 2;
#pragma unroll
  for (int j = 0; j < 4; ++j) {
    float4 v = *reinterpret_cast<const float4*>(
        &s[(size_t)(r0 + j * 16 + lr) * C + c0 + lc]);
    tile[j * 16 + lr][lc + 0] = v.x;
    tile[j * 16 + lr][lc + 1] = v.y;
    tile[j * 16 + lr][lc + 2] = v.z;
    tile[j * 16 + lr][lc + 3] = v.w;
  }
  __syncthreads();
  const int oc = tid >> 3, orr = (tid & 7) << 3;
#pragma unroll
  for (int j = 0; j < 2; ++j) {
    int c = j * 32 + oc;
    u16x8 o;
#pragma unroll
    for (int k = 0; k < 8; ++k) o[k] = f2bf(tile[orr + k][c]);
    *reinterpret_cast<u16x8*>(&d[(size_t)(c0 + c) * R + r0 + orr]) = o;
  }
}

// ---------------- FFN1: inter = gelu(X[perm] @ w_in + b_in), bf16 out --------
// m97 structure: 128x128 tile, BK=64, 256 thr (4 waves 2x2, 64x64/wave),
// single-buffer 32KB LDS, 2-barrier loop (multi-block/CU residency hides the
// barrier drain; compiler emits the vmcnt drain at s_barrier itself).
// T2 chunk-swizzle. Compact grid 32nb * RB128, nb-major.
__global__ void __launch_bounds__(256, 3) ffn1_kernel(
    const unsigned short* __restrict__ xb,
    const unsigned short* __restrict__ win_t,  // [E][I][H]
    const float* __restrict__ b_in,            // [E][I]
    const int* __restrict__ counts,
    const int* __restrict__ perm,
    unsigned short* __restrict__ inter) {
  const int logical = xcd_swz(blockIdx.x, 32 * RB128);
  const int nb = logical / RB128;  // 0..31, consecutive logicals share B panel
  const int g = logical % RB128;
  int e, mb, cnt;
  if (!rb_lookup(counts, g, &e, &mb, &cnt)) return;

  __shared__ char smem[32768];  // A 16KB | B 16KB (epilogue: 4 x 8KB slices)

  const int tid = threadIdx.x;
  int tokr[4];
#pragma unroll
  for (int it = 0; it < 4; ++it) {
    int r = (it * 256 + tid) >> 3;  // 0..127
    tokr[it] = perm[e * CAP + min(mb * 128 + r, cnt - 1)];
  }

  const int wave = tid >> 6, lane = tid & 63;
  const int wr = wave >> 1, wn = wave & 1;  // 2M x 2N
  const int l16 = lane & 15, l4 = lane >> 4;
  const unsigned short* Bbase =
      win_t + (size_t)e * I_DIM * H_DIM + (size_t)(nb * 128) * H_DIM;

  f32x4 acc[4][4] = {};

  const int NK = H_DIM / 64;  // 16
  for (int kt = 0; kt < NK; ++kt) {
    __syncthreads();  // all waves done reading smem (prev iter)
#pragma unroll
    for (int it = 0; it < 4; ++it) {
      int id = it * 256 + tid;
      int r = id >> 3;
      int cs = (id & 7) ^ (r & 7);  // T2: pre-swizzled source chunk
      lds_load16(xb + (size_t)tokr[it] * H_DIM + kt * 64 + cs * 8,
                 smem + id * 16);
      lds_load16(Bbase + (size_t)r * H_DIM + kt * 64 + cs * 8,
                 smem + 16384 + id * 16);
    }
    __syncthreads();  // compiler drains vmcnt(0) here (m97 asm behavior)
#pragma unroll
    for (int kk = 0; kk < 2; ++kk) {
      bf16x8 af[4], bv[4];
#pragma unroll
      for (int m = 0; m < 4; ++m)
        af[m] = *lds_frag(smem, wr * 64 + m * 16 + l16, kk * 4 + l4);
#pragma unroll
      for (int n = 0; n < 4; ++n)
        bv[n] = *lds_frag(smem + 16384, wn * 64 + n * 16 + l16, kk * 4 + l4);
#pragma unroll
      for (int m = 0; m < 4; ++m)
#pragma unroll
        for (int n = 0; n < 4; ++n)
          acc[m][n] =
              __builtin_amdgcn_mfma_f32_16x16x32_bf16(af[m], bv[n], acc[m][n], 0, 0, 0);
    }
  }

  // ---- epilogue: GELU, coalesce via per-wave 8KB LDS slice ----
  __syncthreads();  // all waves done with staging LDS
  const size_t rowbase = (size_t)g * 128;
  unsigned short* slice = (unsigned short*)(smem + wave * 8192);
#pragma unroll
  for (int n = 0; n < 4; ++n) {
    float bias = b_in[e * I_DIM + nb * 128 + wn * 64 + n * 16 + l16];
#pragma unroll
    for (int m = 0; m < 4; ++m) {
#pragma unroll
      for (int j = 0; j < 4; ++j) {
        float v = acc[m][n][j] + bias;
        // tanh-form GELU: v * sigmoid(1.59577(v + 0.044715 v^3)); |err| <~1e-3
        float t = __expf(-1.5957691216057308f * v - 0.07135481627f * v * v * v);
        float gg = v / (1.f + t);
        slice[(m * 16 + l4 * 4 + j) * 64 + n * 16 + l16] = f2bf(gg);
      }
    }
  }
  __syncthreads();  // slice writes visible before cross-lane readback
#pragma unroll
  for (int it = 0; it < 8; ++it) {
    int row = it * 8 + (lane >> 3);        // 0..63
    int colb = (lane & 7) * 8;             // 8 bf16 = 16B
    u16x8 v = *(const u16x8*)&slice[row * 64 + colb];
    *(u16x8*)&inter[(rowbase + wr * 64 + row) * (size_t)I_DIM + nb * 128 +
                    wn * 64 + colb] = v;
  }
}

// ---------------- FFN2: y[slot] = inter @ w_out + b_out (dense, no atomics) --
// m97 structure, 128x128 tile. A-MAJOR grid (g-major): the 8 nb-blocks sharing
// one A-panel co-reside per XCD (keeps the FETCH win). grid 576, ~528 active.
__global__ void __launch_bounds__(256, 3) ffn2_kernel(
    const unsigned short* __restrict__ inter,
    const unsigned short* __restrict__ wout_t,  // [E][H][I]
    const float* __restrict__ b_out,            // [E][H]
    const int* __restrict__ counts,
    float* __restrict__ y) {                    // [slot][H]
  const int logical = xcd_swz(blockIdx.x, RB128 * 8);
  const int g = logical >> 3;      // consecutive logicals share A panel
  const int nb = logical & 7;
  int e, mb, cnt;
  if (!rb_lookup(counts, g, &e, &mb, &cnt)) return;
  (void)mb;

  __shared__ char smem[32768];  // A 16KB | B 16KB

  const int tid = threadIdx.x;
  const int wave = tid >> 6, lane = tid & 63;
  const int wr = wave >> 1, wn = wave & 1;  // 2M x 2N
  const int l16 = lane & 15, l4 = lane >> 4;
  const unsigned short* Bbase =
      wout_t + (size_t)e * H_DIM * I_DIM + (size_t)(nb * 128) * I_DIM;
  const size_t rowbase = (size_t)g * 128;

  f32x4 acc[4][4] = {};

  const int NK = I_DIM / 64;  // 64
  for (int kt = 0; kt < NK; ++kt) {
    __syncthreads();
#pragma unroll
    for (int it = 0; it < 4; ++it) {
      int id = it * 256 + tid;
      int r = id >> 3;
      int cs = (id & 7) ^ (r & 7);
      lds_load16(inter + (rowbase + r) * (size_t)I_DIM + kt * 64 + cs * 8,
                 smem + id * 16);
      lds_load16(Bbase + (size_t)r * I_DIM + kt * 64 + cs * 8,
                 smem + 16384 + id * 16);
    }
    __syncthreads();
#pragma unroll
    for (int kk = 0; kk < 2; ++kk) {
      bf16x8 af[4], bv[4];
#pragma unroll
      for (int m = 0; m < 4; ++m)
        af[m] = *lds_frag(smem, wr * 64 + m * 16 + l16, kk * 4 + l4);
#pragma unroll
      for (int n = 0; n < 4; ++n)
        bv[n] = *lds_frag(smem + 16384, wn * 64 + n * 16 + l16, kk * 4 + l4);
#pragma unroll
      for (int m = 0; m < 4; ++m)
#pragma unroll
        for (int n = 0; n < 4; ++n)
          acc[m][n] =
              __builtin_amdgcn_mfma_f32_16x16x32_bf16(af[m], bv[n], acc[m][n], 0, 0, 0);
    }
  }

  // ---- epilogue: two 32-row passes through per-wave 8KB LDS slice ----
  __syncthreads();
  float* slice = (float*)(smem + wave * 8192);
  float bias[4];
#pragma unroll
  for (int n = 0; n < 4; ++n)
    bias[n] = b_out[e * H_DIM + nb * 128 + wn * 64 + n * 16 + l16];
#pragma unroll
  for (int p = 0; p < 2; ++p) {
#pragma unroll
    for (int mm = 0; mm < 2; ++mm) {
      int m = p * 2 + mm;
#pragma unroll
      for (int n = 0; n < 4; ++n) {
#pragma unroll
        for (int j = 0; j < 4; ++j) {
          slice[(mm * 16 + l4 * 4 + j) * 64 + n * 16 + l16] =
              acc[m][n][j] + bias[n];
        }
      }
    }
    __syncthreads();  // slice writes visible before cross-lane readback
#pragma unroll
    for (int it = 0; it < 8; ++it) {
      int row = it * 4 + (lane >> 4);      // 0..31
      int col = (lane & 15) * 4;           // 4 floats = 16B
      float4 v = *(const float4*)&slice[row * 64 + col];
      *(float4*)&y[(rowbase + wr * 64 + p * 32 + row) * (size_t)H_DIM +
                   nb * 128 + wn * 64 + col] = v;
    }
    __syncthreads();  // readback done before next pass overwrites slice
  }
}

// ---------------- combine: out[t] = w0*y[slot0] + w1*y[slot1] ---------------
__global__ void __launch_bounds__(256) combine_kernel(
    const float* __restrict__ y, const int* __restrict__ counts,
    const int* __restrict__ se, const float* __restrict__ wtok,
    float* __restrict__ out) {
  const int t = blockIdx.x;
  int poff[NE];
  int run = 0;
#pragma unroll
  for (int e = 0; e < NE; ++e) {
    poff[e] = run;
    run += (counts[e] + 127) & ~127;  // must match 128-row block padding
  }
  int c0 = se[2 * t], c1 = se[2 * t + 1];
  float w0 = wtok[2 * t], w1 = wtok[2 * t + 1];
  const float* y0 = y + (size_t)(poff[c0 >> 20] + (c0 & 0xFFFFF)) * H_DIM;
  const float* y1 = y + (size_t)(poff[c1 >> 20] + (c1 & 0xFFFFF)) * H_DIM;
  int h = threadIdx.x * 4;
  float4 a = *reinterpret_cast<const float4*>(y0 + h);
  float4 b = *reinterpret_cast<const float4*>(y1 + h);
  float4 o;
  o.x = w0 * a.x + w1 * b.x;
  o.y = w0 * a.y + w1 * b.y;
  o.z = w0 * a.z + w1 * b.z;
  o.w = w0 * a.w + w1 * b.w;
  *reinterpret_cast<float4*>(out + (size_t)t * H_DIM + h) = o;
}

extern "C" void kernel_launch(void* const* d_in, const int* in_sizes, int n_in,
                              void* d_out, int out_size, void* d_ws, size_t ws_size,
                              hipStream_t stream) {
  const float* x     = (const float*)d_in[0];
  const float* rw    = (const float*)d_in[1];
  const float* w_in  = (const float*)d_in[2];
  const float* b_in  = (const float*)d_in[3];
  const float* w_out = (const float*)d_in[4];
  const float* b_out = (const float*)d_in[5];
  float* out = (float*)d_out;

  char* ws = (char*)d_ws;
  size_t off = 0;
  auto alloc = [&](size_t bytes) {
    char* p = ws + off;
    off = (off + bytes + 255) & ~(size_t)255;
    return p;
  };
  int* counts            = (int*)alloc(NE * 4);
  int* perm              = (int*)alloc((size_t)NE * CAP * 4);
  int* se                = (int*)alloc((size_t)T_TOK * 2 * 4);
  float* wtok            = (float*)alloc((size_t)T_TOK * 2 * 4);
  unsigned short* xb     = (unsigned short*)alloc((size_t)T_TOK * H_DIM * 2);
  unsigned short* win_t  = (unsigned short*)alloc((size_t)NE * H_DIM * I_DIM * 2);
  unsigned short* wout_t = (unsigned short*)alloc((size_t)NE * H_DIM * I_DIM * 2);
  unsigned short* inter  = (unsigned short*)alloc((size_t)(T_TOK * 2 + NE * 256) * I_DIM * 2);
  // y overlays ONLY win_t (dead after ffn1; rewritten by transpose before the
  // next ffn1): need <= 9216*1024*4 = 37.7MB <= 64MB
  float* y = (float*)win_t;
  if (off > ws_size) return;  // ws too small -> visible correctness failure

  hipMemsetAsync(counts, 0, NE * sizeof(int), stream);

  router_convert_kernel<<<T_TOK, 256, 0, stream>>>(x, rw, counts, perm, se,
                                                   wtok, xb);
  transpose_conv2_kernel<<<dim3(64, 16, 16), 256, 0, stream>>>(w_in, w_out,
                                                               win_t, wout_t);
  ffn1_kernel<<<32 * RB128, 256, 0, stream>>>(xb, win_t, b_in, counts, perm,
                                              inter);
  ffn2_kernel<<<RB128 * 8, 256, 0, stream>>>(inter, wout_t, b_out, counts, y);
  combine_kernel<<<T_TOK, 256, 0, stream>>>(y, counts, se, wtok, out);
}

// Round 13
// 374.802 us; speedup vs baseline: 1.1072x; 1.0187x over previous
//
#include <hip/hip_runtime.h>
#include <hip/hip_bf16.h>
#include <stdint.h>

#define NE 8
#define T_TOK 4096
#define H_DIM 1024
#define I_DIM 4096
#define CAP 4096
#define RB128 72  // max total 128-row blocks: 8192/128 + 8 = 72

typedef __attribute__((ext_vector_type(8))) short bf16x8;
typedef __attribute__((ext_vector_type(4))) float f32x4;
typedef __attribute__((ext_vector_type(8))) unsigned short u16x8;

__device__ __forceinline__ unsigned short f2bf(float f) {
  __hip_bfloat16 h = __float2bfloat16(f);
  return *reinterpret_cast<unsigned short*>(&h);
}

__device__ __forceinline__ void lds_load16(const void* g, void* l) {
  __builtin_amdgcn_global_load_lds((__attribute__((address_space(1))) void*)g,
                                   (__attribute__((address_space(3))) void*)l,
                                   16, 0, 0);
}

// swizzled LDS fragment read: tile layout [rows][64 bf16] (128B rows, 8x16B
// chunks); content chunk cc of row lives at physical chunk cc ^ (row&7)
__device__ __forceinline__ const bf16x8* lds_frag(const char* base, int row,
                                                  int cc) {
  return (const bf16x8*)(base + row * 128 + ((cc ^ (row & 7)) << 4));
}

// bijective XCD swizzle (nwg % 8 == 0): each XCD owns a contiguous logical chunk
__device__ __forceinline__ int xcd_swz(int bid, int nwg) {
  return (bid & 7) * (nwg >> 3) + (bid >> 3);
}

// map flat 128-row block g -> (expert e, local block mb); rowbase is 128*g
__device__ __forceinline__ bool rb_lookup(const int* counts, int g, int* e_out,
                                          int* mb_out, int* cnt_out) {
  int acc = 0;
#pragma unroll
  for (int i = 0; i < NE; ++i) {
    int c = counts[i];
    int rb = (c + 127) >> 7;
    if (g < acc + rb) {
      *e_out = i;
      *mb_out = g - acc;
      *cnt_out = c;
      return true;
    }
    acc += rb;
  }
  return false;
}

// 64x64 transpose+convert tile: src f32 [R][C] region (r0,c0) -> dst bf16
// [C][R]. MLP-staged: all 4 float4 loads issued before LDS writes.
__device__ __forceinline__ void transpose_tile(const float* __restrict__ s,
                                               unsigned short* __restrict__ d,
                                               int R, int C, int r0, int c0,
                                               char* shm, int tid) {
  float(*tile)[65] = (float(*)[65])shm;
  const int lr = tid >> 4, lc = (tid & 15) << 2;
  float4 vv[4];
#pragma unroll
  for (int j = 0; j < 4; ++j)
    vv[j] = *reinterpret_cast<const float4*>(
        &s[(size_t)(r0 + j * 16 + lr) * C + c0 + lc]);
#pragma unroll
  for (int j = 0; j < 4; ++j) {
    tile[j * 16 + lr][lc + 0] = vv[j].x;
    tile[j * 16 + lr][lc + 1] = vv[j].y;
    tile[j * 16 + lr][lc + 2] = vv[j].z;
    tile[j * 16 + lr][lc + 3] = vv[j].w;
  }
  __syncthreads();
  const int oc = tid >> 3, orr = (tid & 7) << 3;
#pragma unroll
  for (int j = 0; j < 2; ++j) {
    int c = j * 32 + oc;
    u16x8 o;
#pragma unroll
    for (int k = 0; k < 8; ++k) o[k] = f2bf(tile[orr + k][c]);
    *reinterpret_cast<u16x8*>(&d[(size_t)(c0 + c) * R + r0 + orr]) = o;
  }
}

// ---------------- K1: fused router+convert (4096 blocks) U w_in transpose ----
__global__ void __launch_bounds__(256) prep_kernel(
    const float* __restrict__ x, const float* __restrict__ rw,
    int* __restrict__ counts, int* __restrict__ perm, int* __restrict__ se,
    float* __restrict__ wtok, unsigned short* __restrict__ xb,
    const float* __restrict__ w_in, unsigned short* __restrict__ win_t) {
  __shared__ char shm[16640];  // transpose tile; router uses first 128B
  const int bid = blockIdx.x;
  const int tid = threadIdx.x;

  if (bid < T_TOK) {
    // ---- router + x->bf16 for token t ----
    const int t = bid;
    float(*red)[NE] = (float(*)[NE])shm;
    float4 v = reinterpret_cast<const float4*>(x + (size_t)t * H_DIM)[tid];
    ushort4 o;
    o.x = f2bf(v.x); o.y = f2bf(v.y); o.z = f2bf(v.z); o.w = f2bf(v.w);
    reinterpret_cast<ushort4*>(xb + (size_t)t * H_DIM)[tid] = o;

    float part[NE];
#pragma unroll
    for (int e = 0; e < NE; ++e) {
      float4 w = reinterpret_cast<const float4*>(rw + (size_t)e * H_DIM)[tid];
      part[e] = v.x * w.x + v.y * w.y + v.z * w.z + v.w * w.w;
    }
    const int wave = tid >> 6, lane = tid & 63;
#pragma unroll
    for (int e = 0; e < NE; ++e) {
#pragma unroll
      for (int off = 32; off > 0; off >>= 1)
        part[e] += __shfl_xor(part[e], off);
    }
    if (lane == 0) {
#pragma unroll
      for (int e = 0; e < NE; ++e) red[wave][e] = part[e];
    }
    __syncthreads();
    if (tid == 0) {
      float acc[NE];
#pragma unroll
      for (int e = 0; e < NE; ++e)
        acc[e] = red[0][e] + red[1][e] + red[2][e] + red[3][e];
      int i0 = 0;
#pragma unroll
      for (int e = 1; e < NE; ++e)
        if (acc[e] > acc[i0]) i0 = e;
      int i1 = (i0 == 0) ? 1 : 0;
#pragma unroll
      for (int e = 0; e < NE; ++e)
        if (e != i0 && acc[e] > acc[i1]) i1 = e;
      float la = acc[i0], lb = acc[i1];
      float r = expf(lb - la);          // <= 1
      float wa = 1.f / (1.f + r);       // normalized top-2 softmax weights
      float wb = 1.f - wa;
      int p0 = atomicAdd(&counts[i0], 1);
      perm[i0 * CAP + p0] = t;
      se[2 * t + 0] = (i0 << 20) | p0;
      wtok[2 * t + 0] = wa;
      int p1 = atomicAdd(&counts[i1], 1);
      perm[i1 * CAP + p1] = t;
      se[2 * t + 1] = (i1 << 20) | p1;
      wtok[2 * t + 1] = wb;
    }
  } else {
    // ---- w_in [e][1024][4096] -> win_t [e][4096][1024] ----
    const int idx = bid - T_TOK;
    const int e = idx >> 10, rem = idx & 1023;
    const int c0 = (rem & 63) * 64, r0 = (rem >> 6) * 64;  // C=4096, R=1024
    transpose_tile(w_in + (size_t)e * H_DIM * I_DIM,
                   win_t + (size_t)e * H_DIM * I_DIM, H_DIM, I_DIM, r0, c0,
                   shm, tid);
  }
}

// ---------------- K2: ffn1 (2304 blocks, first) U w_out transpose (8192) ----
// ffn1: m97 structure, 128x128 tile, BK=64, 256 thr, single-buffer 32KB LDS,
// 2-barrier loop, T2 chunk-swizzle, compact nb-major grid. The w_out
// transpose blocks backfill ffn1's latency/barrier gaps (wout_t is consumed
// only by the NEXT kernel -> no intra-launch ordering needed).
__global__ void __launch_bounds__(256, 3) ffn1_wout_kernel(
    const unsigned short* __restrict__ xb,
    const unsigned short* __restrict__ win_t,  // [E][I][H]
    const float* __restrict__ b_in,            // [E][I]
    const int* __restrict__ counts,
    const int* __restrict__ perm,
    unsigned short* __restrict__ inter,
    const float* __restrict__ w_out,
    unsigned short* __restrict__ wout_t) {
  __shared__ char smem[32768];
  const int bid = blockIdx.x;
  const int tid = threadIdx.x;

  if (bid >= 32 * RB128) {
    // ---- w_out [e][4096][1024] -> wout_t [e][1024][4096] ----
    const int idx = bid - 32 * RB128;
    const int e = idx >> 10, rem = idx & 1023;
    const int c0 = (rem & 15) * 64, r0 = (rem >> 4) * 64;  // C=1024, R=4096
    transpose_tile(w_out + (size_t)e * H_DIM * I_DIM,
                   wout_t + (size_t)e * H_DIM * I_DIM, I_DIM, H_DIM, r0, c0,
                   smem, tid);
    return;
  }

  const int logical = xcd_swz(bid, 32 * RB128);
  const int nb = logical / RB128;  // 0..31, consecutive logicals share B panel
  const int g = logical % RB128;
  int e, mb, cnt;
  if (!rb_lookup(counts, g, &e, &mb, &cnt)) return;

  int tokr[4];
#pragma unroll
  for (int it = 0; it < 4; ++it) {
    int r = (it * 256 + tid) >> 3;  // 0..127
    tokr[it] = perm[e * CAP + min(mb * 128 + r, cnt - 1)];
  }

  const int wave = tid >> 6, lane = tid & 63;
  const int wr = wave >> 1, wn = wave & 1;  // 2M x 2N
  const int l16 = lane & 15, l4 = lane >> 4;
  const unsigned short* Bbase =
      win_t + (size_t)e * I_DIM * H_DIM + (size_t)(nb * 128) * H_DIM;

  f32x4 acc[4][4] = {};

  const int NK = H_DIM / 64;  // 16
  for (int kt = 0; kt < NK; ++kt) {
    __syncthreads();  // all waves done reading smem (prev iter)
#pragma unroll
    for (int it = 0; it < 4; ++it) {
      int id = it * 256 + tid;
      int r = id >> 3;
      int cs = (id & 7) ^ (r & 7);  // T2: pre-swizzled source chunk
      lds_load16(xb + (size_t)tokr[it] * H_DIM + kt * 64 + cs * 8,
                 smem + id * 16);
      lds_load16(Bbase + (size_t)r * H_DIM + kt * 64 + cs * 8,
                 smem + 16384 + id * 16);
    }
    __syncthreads();  // compiler drains vmcnt(0) here (m97 asm behavior)
#pragma unroll
    for (int kk = 0; kk < 2; ++kk) {
      bf16x8 af[4], bv[4];
#pragma unroll
      for (int m = 0; m < 4; ++m)
        af[m] = *lds_frag(smem, wr * 64 + m * 16 + l16, kk * 4 + l4);
#pragma unroll
      for (int n = 0; n < 4; ++n)
        bv[n] = *lds_frag(smem + 16384, wn * 64 + n * 16 + l16, kk * 4 + l4);
#pragma unroll
      for (int m = 0; m < 4; ++m)
#pragma unroll
        for (int n = 0; n < 4; ++n)
          acc[m][n] =
              __builtin_amdgcn_mfma_f32_16x16x32_bf16(af[m], bv[n], acc[m][n], 0, 0, 0);
    }
  }

  // ---- epilogue: GELU, coalesce via per-wave 8KB LDS slice ----
  __syncthreads();  // all waves done with staging LDS
  const size_t rowbase = (size_t)g * 128;
  unsigned short* slice = (unsigned short*)(smem + wave * 8192);
#pragma unroll
  for (int n = 0; n < 4; ++n) {
    float bias = b_in[e * I_DIM + nb * 128 + wn * 64 + n * 16 + l16];
#pragma unroll
    for (int m = 0; m < 4; ++m) {
#pragma unroll
      for (int j = 0; j < 4; ++j) {
        float v = acc[m][n][j] + bias;
        // tanh-form GELU: v * sigmoid(1.59577(v + 0.044715 v^3)); |err| <~1e-3
        float t = __expf(-1.5957691216057308f * v - 0.07135481627f * v * v * v);
        float gg = v / (1.f + t);
        slice[(m * 16 + l4 * 4 + j) * 64 + n * 16 + l16] = f2bf(gg);
      }
    }
  }
  __syncthreads();  // slice writes visible before cross-lane readback
#pragma unroll
  for (int it = 0; it < 8; ++it) {
    int row = it * 8 + (lane >> 3);        // 0..63
    int colb = (lane & 7) * 8;             // 8 bf16 = 16B
    u16x8 v = *(const u16x8*)&slice[row * 64 + colb];
    *(u16x8*)&inter[(rowbase + wr * 64 + row) * (size_t)I_DIM + nb * 128 +
                    wn * 64 + colb] = v;
  }
}

// ---------------- FFN2: y[slot] = inter @ w_out + b_out (dense, no atomics) --
// m97 structure, 128x128 tile. A-MAJOR grid (g-major): the 8 nb-blocks sharing
// one A-panel co-reside per XCD (keeps the FETCH win). grid 576, ~528 active.
__global__ void __launch_bounds__(256, 3) ffn2_kernel(
    const unsigned short* __restrict__ inter,
    const unsigned short* __restrict__ wout_t,  // [E][H][I]
    const float* __restrict__ b_out,            // [E][H]
    const int* __restrict__ counts,
    float* __restrict__ y) {                    // [slot][H]
  const int logical = xcd_swz(blockIdx.x, RB128 * 8);
  const int g = logical >> 3;      // consecutive logicals share A panel
  const int nb = logical & 7;
  int e, mb, cnt;
  if (!rb_lookup(counts, g, &e, &mb, &cnt)) return;
  (void)mb;

  __shared__ char smem[32768];  // A 16KB | B 16KB

  const int tid = threadIdx.x;
  const int wave = tid >> 6, lane = tid & 63;
  const int wr = wave >> 1, wn = wave & 1;  // 2M x 2N
  const int l16 = lane & 15, l4 = lane >> 4;
  const unsigned short* Bbase =
      wout_t + (size_t)e * H_DIM * I_DIM + (size_t)(nb * 128) * I_DIM;
  const size_t rowbase = (size_t)g * 128;

  f32x4 acc[4][4] = {};

  const int NK = I_DIM / 64;  // 64
  for (int kt = 0; kt < NK; ++kt) {
    __syncthreads();
#pragma unroll
    for (int it = 0; it < 4; ++it) {
      int id = it * 256 + tid;
      int r = id >> 3;
      int cs = (id & 7) ^ (r & 7);
      lds_load16(inter + (rowbase + r) * (size_t)I_DIM + kt * 64 + cs * 8,
                 smem + id * 16);
      lds_load16(Bbase + (size_t)r * I_DIM + kt * 64 + cs * 8,
                 smem + 16384 + id * 16);
    }
    __syncthreads();
#pragma unroll
    for (int kk = 0; kk < 2; ++kk) {
      bf16x8 af[4], bv[4];
#pragma unroll
      for (int m = 0; m < 4; ++m)
        af[m] = *lds_frag(smem, wr * 64 + m * 16 + l16, kk * 4 + l4);
#pragma unroll
      for (int n = 0; n < 4; ++n)
        bv[n] = *lds_frag(smem + 16384, wn * 64 + n * 16 + l16, kk * 4 + l4);
#pragma unroll
      for (int m = 0; m < 4; ++m)
#pragma unroll
        for (int n = 0; n < 4; ++n)
          acc[m][n] =
              __builtin_amdgcn_mfma_f32_16x16x32_bf16(af[m], bv[n], acc[m][n], 0, 0, 0);
    }
  }

  // ---- epilogue: two 32-row passes through per-wave 8KB LDS slice ----
  __syncthreads();
  float* slice = (float*)(smem + wave * 8192);
  float bias[4];
#pragma unroll
  for (int n = 0; n < 4; ++n)
    bias[n] = b_out[e * H_DIM + nb * 128 + wn * 64 + n * 16 + l16];
#pragma unroll
  for (int p = 0; p < 2; ++p) {
#pragma unroll
    for (int mm = 0; mm < 2; ++mm) {
      int m = p * 2 + mm;
#pragma unroll
      for (int n = 0; n < 4; ++n) {
#pragma unroll
        for (int j = 0; j < 4; ++j) {
          slice[(mm * 16 + l4 * 4 + j) * 64 + n * 16 + l16] =
              acc[m][n][j] + bias[n];
        }
      }
    }
    __syncthreads();  // slice writes visible before cross-lane readback
#pragma unroll
    for (int it = 0; it < 8; ++it) {
      int row = it * 4 + (lane >> 4);      // 0..31
      int col = (lane & 15) * 4;           // 4 floats = 16B
      float4 v = *(const float4*)&slice[row * 64 + col];
      *(float4*)&y[(rowbase + wr * 64 + p * 32 + row) * (size_t)H_DIM +
                   nb * 128 + wn * 64 + col] = v;
    }
    __syncthreads();  // readback done before next pass overwrites slice
  }
}

// ---------------- combine: out[t] = w0*y[slot0] + w1*y[slot1] ---------------
__global__ void __launch_bounds__(256) combine_kernel(
    const float* __restrict__ y, const int* __restrict__ counts,
    const int* __restrict__ se, const float* __restrict__ wtok,
    float* __restrict__ out) {
  const int t = blockIdx.x;
  int poff[NE];
  int run = 0;
#pragma unroll
  for (int e = 0; e < NE; ++e) {
    poff[e] = run;
    run += (counts[e] + 127) & ~127;  // must match 128-row block padding
  }
  int c0 = se[2 * t], c1 = se[2 * t + 1];
  float w0 = wtok[2 * t], w1 = wtok[2 * t + 1];
  const float* y0 = y + (size_t)(poff[c0 >> 20] + (c0 & 0xFFFFF)) * H_DIM;
  const float* y1 = y + (size_t)(poff[c1 >> 20] + (c1 & 0xFFFFF)) * H_DIM;
  int h = threadIdx.x * 4;
  float4 a = *reinterpret_cast<const float4*>(y0 + h);
  float4 b = *reinterpret_cast<const float4*>(y1 + h);
  float4 o;
  o.x = w0 * a.x + w1 * b.x;
  o.y = w0 * a.y + w1 * b.y;
  o.z = w0 * a.z + w1 * b.z;
  o.w = w0 * a.w + w1 * b.w;
  *reinterpret_cast<float4*>(out + (size_t)t * H_DIM + h) = o;
}

extern "C" void kernel_launch(void* const* d_in, const int* in_sizes, int n_in,
                              void* d_out, int out_size, void* d_ws, size_t ws_size,
                              hipStream_t stream) {
  const float* x     = (const float*)d_in[0];
  const float* rw    = (const float*)d_in[1];
  const float* w_in  = (const float*)d_in[2];
  const float* b_in  = (const float*)d_in[3];
  const float* w_out = (const float*)d_in[4];
  const float* b_out = (const float*)d_in[5];
  float* out = (float*)d_out;

  char* ws = (char*)d_ws;
  size_t off = 0;
  auto alloc = [&](size_t bytes) {
    char* p = ws + off;
    off = (off + bytes + 255) & ~(size_t)255;
    return p;
  };
  int* counts            = (int*)alloc(NE * 4);
  int* perm              = (int*)alloc((size_t)NE * CAP * 4);
  int* se                = (int*)alloc((size_t)T_TOK * 2 * 4);
  float* wtok            = (float*)alloc((size_t)T_TOK * 2 * 4);
  unsigned short* xb     = (unsigned short*)alloc((size_t)T_TOK * H_DIM * 2);
  unsigned short* win_t  = (unsigned short*)alloc((size_t)NE * H_DIM * I_DIM * 2);
  unsigned short* wout_t = (unsigned short*)alloc((size_t)NE * H_DIM * I_DIM * 2);
  unsigned short* inter  = (unsigned short*)alloc((size_t)(T_TOK * 2 + NE * 256) * I_DIM * 2);
  // y overlays ONLY win_t (read-dead after K2's ffn1 part; rewritten by K1's
  // transpose before the next ffn1): need <= 9216*1024*4 = 37.7MB <= 64MB
  float* y = (float*)win_t;
  if (off > ws_size) return;  // ws too small -> visible correctness failure

  hipMemsetAsync(counts, 0, NE * sizeof(int), stream);

  prep_kernel<<<T_TOK + NE * 1024, 256, 0, stream>>>(x, rw, counts, perm, se,
                                                     wtok, xb, w_in, win_t);
  ffn1_wout_kernel<<<32 * RB128 + NE * 1024, 256, 0, stream>>>(
      xb, win_t, b_in, counts, perm, inter, w_out, wout_t);
  ffn2_kernel<<<RB128 * 8, 256, 0, stream>>>(inter, wout_t, b_out, counts, y);
  combine_kernel<<<T_TOK, 256, 0, stream>>>(y, counts, se, wtok, out);
}

// Round 14
// 292.728 us; speedup vs baseline: 1.4177x; 1.2804x over previous
//
#include <hip/hip_runtime.h>
#include <hip/hip_bf16.h>
#include <stdint.h>

#define NE 8
#define T_TOK 4096
#define H_DIM 1024
#define I_DIM 4096
#define CAP 4096
#define RB128 72  // max total 128-row blocks: 8192/128 + 8 = 72

typedef __attribute__((ext_vector_type(8))) short bf16x8;
typedef __attribute__((ext_vector_type(4))) float f32x4;
typedef __attribute__((ext_vector_type(8))) unsigned short u16x8;

__device__ __forceinline__ unsigned short f2bf(float f) {
  __hip_bfloat16 h = __float2bfloat16(f);
  return *reinterpret_cast<unsigned short*>(&h);
}

__device__ __forceinline__ void lds_load16(const void* g, void* l) {
  __builtin_amdgcn_global_load_lds((__attribute__((address_space(1))) void*)g,
                                   (__attribute__((address_space(3))) void*)l,
                                   16, 0, 0);
}

// swizzled LDS fragment read: tile layout [rows][64 bf16] (128B rows, 8x16B
// chunks); content chunk cc of row lives at physical chunk cc ^ (row&7)
__device__ __forceinline__ const bf16x8* lds_frag(const char* base, int row,
                                                  int cc) {
  return (const bf16x8*)(base + row * 128 + ((cc ^ (row & 7)) << 4));
}

// bijective XCD swizzle (nwg % 8 == 0): each XCD owns a contiguous logical chunk
__device__ __forceinline__ int xcd_swz(int bid, int nwg) {
  return (bid & 7) * (nwg >> 3) + (bid >> 3);
}

// map flat 128-row block g -> (expert e, local block mb); rowbase is 128*g
__device__ __forceinline__ bool rb_lookup(const int* counts, int g, int* e_out,
                                          int* mb_out, int* cnt_out) {
  int acc = 0;
#pragma unroll
  for (int i = 0; i < NE; ++i) {
    int c = counts[i];
    int rb = (c + 127) >> 7;
    if (g < acc + rb) {
      *e_out = i;
      *mb_out = g - acc;
      *cnt_out = c;
      return true;
    }
    acc += rb;
  }
  return false;
}

// 64x64 transpose+convert tile: src f32 [R][C] region (r0,c0) -> dst bf16
// [C][R]. MLP-staged: all 4 float4 loads issued before LDS writes.
__device__ __forceinline__ void transpose_tile(const float* __restrict__ s,
                                               unsigned short* __restrict__ d,
                                               int R, int C, int r0, int c0,
                                               char* shm, int tid) {
  float(*tile)[65] = (float(*)[65])shm;
  const int lr = tid >> 4, lc = (tid & 15) << 2;
  float4 vv[4];
#pragma unroll
  for (int j = 0; j < 4; ++j)
    vv[j] = *reinterpret_cast<const float4*>(
        &s[(size_t)(r0 + j * 16 + lr) * C + c0 + lc]);
#pragma unroll
  for (int j = 0; j < 4; ++j) {
    tile[j * 16 + lr][lc + 0] = vv[j].x;
    tile[j * 16 + lr][lc + 1] = vv[j].y;
    tile[j * 16 + lr][lc + 2] = vv[j].z;
    tile[j * 16 + lr][lc + 3] = vv[j].w;
  }
  __syncthreads();
  const int oc = tid >> 3, orr = (tid & 7) << 3;
#pragma unroll
  for (int j = 0; j < 2; ++j) {
    int c = j * 32 + oc;
    u16x8 o;
#pragma unroll
    for (int k = 0; k < 8; ++k) o[k] = f2bf(tile[orr + k][c]);
    *reinterpret_cast<u16x8*>(&d[(size_t)(c0 + c) * R + r0 + orr]) = o;
  }
}

// ---------------- K1: router (NO atomics) U w_in transpose ----
// router blocks write only top2e/wtok (pure streaming); ranking deferred to
// bucketize. Removes the 8192 same-line far-atomics that serialized r13 prep.
__global__ void __launch_bounds__(256) prep_kernel(
    const float* __restrict__ x, const float* __restrict__ rw,
    int* __restrict__ top2e, float* __restrict__ wtok,
    unsigned short* __restrict__ xb, const float* __restrict__ w_in,
    unsigned short* __restrict__ win_t) {
  __shared__ char shm[16640];  // transpose tile; router uses first 128B
  const int bid = blockIdx.x;
  const int tid = threadIdx.x;

  if (bid < T_TOK) {
    // ---- router + x->bf16 for token t ----
    const int t = bid;
    float(*red)[NE] = (float(*)[NE])shm;
    float4 v = reinterpret_cast<const float4*>(x + (size_t)t * H_DIM)[tid];
    ushort4 o;
    o.x = f2bf(v.x); o.y = f2bf(v.y); o.z = f2bf(v.z); o.w = f2bf(v.w);
    reinterpret_cast<ushort4*>(xb + (size_t)t * H_DIM)[tid] = o;

    float part[NE];
#pragma unroll
    for (int e = 0; e < NE; ++e) {
      float4 w = reinterpret_cast<const float4*>(rw + (size_t)e * H_DIM)[tid];
      part[e] = v.x * w.x + v.y * w.y + v.z * w.z + v.w * w.w;
    }
    const int wave = tid >> 6, lane = tid & 63;
#pragma unroll
    for (int e = 0; e < NE; ++e) {
#pragma unroll
      for (int off = 32; off > 0; off >>= 1)
        part[e] += __shfl_xor(part[e], off);
    }
    if (lane == 0) {
#pragma unroll
      for (int e = 0; e < NE; ++e) red[wave][e] = part[e];
    }
    __syncthreads();
    if (tid == 0) {
      float acc[NE];
#pragma unroll
      for (int e = 0; e < NE; ++e)
        acc[e] = red[0][e] + red[1][e] + red[2][e] + red[3][e];
      int i0 = 0;
#pragma unroll
      for (int e = 1; e < NE; ++e)
        if (acc[e] > acc[i0]) i0 = e;
      int i1 = (i0 == 0) ? 1 : 0;
#pragma unroll
      for (int e = 0; e < NE; ++e)
        if (e != i0 && acc[e] > acc[i1]) i1 = e;
      float la = acc[i0], lb = acc[i1];
      float r = expf(lb - la);          // <= 1
      float wa = 1.f / (1.f + r);       // normalized top-2 softmax weights
      float wb = 1.f - wa;
      top2e[2 * t + 0] = i0;
      wtok[2 * t + 0] = wa;
      top2e[2 * t + 1] = i1;
      wtok[2 * t + 1] = wb;
    }
  } else {
    // ---- w_in [e][1024][4096] -> win_t [e][4096][1024] ----
    const int idx = bid - T_TOK;
    const int e = idx >> 10, rem = idx & 1023;
    const int c0 = (rem & 63) * 64, r0 = (rem >> 6) * 64;  // C=4096, R=1024
    transpose_tile(w_in + (size_t)e * H_DIM * I_DIM,
                   win_t + (size_t)e * H_DIM * I_DIM, H_DIM, I_DIM, r0, c0,
                   shm, tid);
  }
}

// ---------------- bucketize: deterministic counting-rank, no atomics ----
// 8 blocks (one per expert) x 1024 threads; each thread owns 8 entries.
// Prefix-scan of per-thread match counts -> positions; writes counts, perm,
// se[entry] = (e<<20)|pos. Each entry has exactly one expert -> no conflicts.
__global__ void __launch_bounds__(1024) bucketize_kernel(
    const int* __restrict__ top2e, int* __restrict__ counts,
    int* __restrict__ perm, int* __restrict__ se) {
  const int e = blockIdx.x;
  const int tid = threadIdx.x;
  __shared__ int wsum[16];
  int my[8];
  int cnt = 0;
#pragma unroll
  for (int j = 0; j < 8; ++j) {
    my[j] = top2e[tid * 8 + j];
    cnt += (my[j] == e) ? 1 : 0;
  }
  const int lane = tid & 63, wave = tid >> 6;
  int scan = cnt;  // inclusive wave scan
#pragma unroll
  for (int off = 1; off < 64; off <<= 1) {
    int v = __shfl_up(scan, off);
    if (lane >= off) scan += v;
  }
  if (lane == 63) wsum[wave] = scan;
  __syncthreads();
  int wbase = 0;
#pragma unroll
  for (int w = 0; w < 16; ++w)
    if (w < wave) wbase += wsum[w];
  int pos = wbase + scan - cnt;  // exclusive prefix for this thread
#pragma unroll
  for (int j = 0; j < 8; ++j) {
    if (my[j] == e) {
      int entry = tid * 8 + j;
      perm[e * CAP + pos] = entry >> 1;
      se[entry] = (e << 20) | pos;
      ++pos;
    }
  }
  if (tid == 1023) counts[e] = pos;
}

// ---------------- K2: ffn1 (2304 blocks, first) U w_out transpose (8192) ----
// ffn1: m97 structure, 128x128 tile, BK=64, 256 thr, single-buffer 32KB LDS,
// 2-barrier loop, T2 chunk-swizzle, compact nb-major grid. The w_out
// transpose blocks backfill ffn1's latency/barrier gaps (wout_t is consumed
// only by the NEXT kernel -> no intra-launch ordering needed).
__global__ void __launch_bounds__(256, 3) ffn1_wout_kernel(
    const unsigned short* __restrict__ xb,
    const unsigned short* __restrict__ win_t,  // [E][I][H]
    const float* __restrict__ b_in,            // [E][I]
    const int* __restrict__ counts,
    const int* __restrict__ perm,
    unsigned short* __restrict__ inter,
    const float* __restrict__ w_out,
    unsigned short* __restrict__ wout_t) {
  __shared__ char smem[32768];
  const int bid = blockIdx.x;
  const int tid = threadIdx.x;

  if (bid >= 32 * RB128) {
    // ---- w_out [e][4096][1024] -> wout_t [e][1024][4096] ----
    const int idx = bid - 32 * RB128;
    const int e = idx >> 10, rem = idx & 1023;
    const int c0 = (rem & 15) * 64, r0 = (rem >> 4) * 64;  // C=1024, R=4096
    transpose_tile(w_out + (size_t)e * H_DIM * I_DIM,
                   wout_t + (size_t)e * H_DIM * I_DIM, I_DIM, H_DIM, r0, c0,
                   smem, tid);
    return;
  }

  const int logical = xcd_swz(bid, 32 * RB128);
  const int nb = logical / RB128;  // 0..31, consecutive logicals share B panel
  const int g = logical % RB128;
  int e, mb, cnt;
  if (!rb_lookup(counts, g, &e, &mb, &cnt)) return;

  int tokr[4];
#pragma unroll
  for (int it = 0; it < 4; ++it) {
    int r = (it * 256 + tid) >> 3;  // 0..127
    tokr[it] = perm[e * CAP + min(mb * 128 + r, cnt - 1)];
  }

  const int wave = tid >> 6, lane = tid & 63;
  const int wr = wave >> 1, wn = wave & 1;  // 2M x 2N
  const int l16 = lane & 15, l4 = lane >> 4;
  const unsigned short* Bbase =
      win_t + (size_t)e * I_DIM * H_DIM + (size_t)(nb * 128) * H_DIM;

  f32x4 acc[4][4] = {};

  const int NK = H_DIM / 64;  // 16
  for (int kt = 0; kt < NK; ++kt) {
    __syncthreads();  // all waves done reading smem (prev iter)
#pragma unroll
    for (int it = 0; it < 4; ++it) {
      int id = it * 256 + tid;
      int r = id >> 3;
      int cs = (id & 7) ^ (r & 7);  // T2: pre-swizzled source chunk
      lds_load16(xb + (size_t)tokr[it] * H_DIM + kt * 64 + cs * 8,
                 smem + id * 16);
      lds_load16(Bbase + (size_t)r * H_DIM + kt * 64 + cs * 8,
                 smem + 16384 + id * 16);
    }
    __syncthreads();  // compiler drains vmcnt(0) here (m97 asm behavior)
#pragma unroll
    for (int kk = 0; kk < 2; ++kk) {
      bf16x8 af[4], bv[4];
#pragma unroll
      for (int m = 0; m < 4; ++m)
        af[m] = *lds_frag(smem, wr * 64 + m * 16 + l16, kk * 4 + l4);
#pragma unroll
      for (int n = 0; n < 4; ++n)
        bv[n] = *lds_frag(smem + 16384, wn * 64 + n * 16 + l16, kk * 4 + l4);
#pragma unroll
      for (int m = 0; m < 4; ++m)
#pragma unroll
        for (int n = 0; n < 4; ++n)
          acc[m][n] =
              __builtin_amdgcn_mfma_f32_16x16x32_bf16(af[m], bv[n], acc[m][n], 0, 0, 0);
    }
  }

  // ---- epilogue: GELU, coalesce via per-wave 8KB LDS slice ----
  __syncthreads();  // all waves done with staging LDS
  const size_t rowbase = (size_t)g * 128;
  unsigned short* slice = (unsigned short*)(smem + wave * 8192);
#pragma unroll
  for (int n = 0; n < 4; ++n) {
    float bias = b_in[e * I_DIM + nb * 128 + wn * 64 + n * 16 + l16];
#pragma unroll
    for (int m = 0; m < 4; ++m) {
#pragma unroll
      for (int j = 0; j < 4; ++j) {
        float v = acc[m][n][j] + bias;
        // tanh-form GELU: v * sigmoid(1.59577(v + 0.044715 v^3)); |err| <~1e-3
        float t = __expf(-1.5957691216057308f * v - 0.07135481627f * v * v * v);
        float gg = v / (1.f + t);
        slice[(m * 16 + l4 * 4 + j) * 64 + n * 16 + l16] = f2bf(gg);
      }
    }
  }
  __syncthreads();  // slice writes visible before cross-lane readback
#pragma unroll
  for (int it = 0; it < 8; ++it) {
    int row = it * 8 + (lane >> 3);        // 0..63
    int colb = (lane & 7) * 8;             // 8 bf16 = 16B
    u16x8 v = *(const u16x8*)&slice[row * 64 + colb];
    *(u16x8*)&inter[(rowbase + wr * 64 + row) * (size_t)I_DIM + nb * 128 +
                    wn * 64 + colb] = v;
  }
}

// ---------------- FFN2: y[slot] = inter @ w_out + b_out (dense, no atomics) --
// m97 structure, 128x128 tile. A-MAJOR grid (g-major): the 8 nb-blocks sharing
// one A-panel co-reside per XCD (keeps the FETCH win). grid 576, ~528 active.
__global__ void __launch_bounds__(256, 3) ffn2_kernel(
    const unsigned short* __restrict__ inter,
    const unsigned short* __restrict__ wout_t,  // [E][H][I]
    const float* __restrict__ b_out,            // [E][H]
    const int* __restrict__ counts,
    float* __restrict__ y) {                    // [slot][H]
  const int logical = xcd_swz(blockIdx.x, RB128 * 8);
  const int g = logical >> 3;      // consecutive logicals share A panel
  const int nb = logical & 7;
  int e, mb, cnt;
  if (!rb_lookup(counts, g, &e, &mb, &cnt)) return;
  (void)mb;

  __shared__ char smem[32768];  // A 16KB | B 16KB

  const int tid = threadIdx.x;
  const int wave = tid >> 6, lane = tid & 63;
  const int wr = wave >> 1, wn = wave & 1;  // 2M x 2N
  const int l16 = lane & 15, l4 = lane >> 4;
  const unsigned short* Bbase =
      wout_t + (size_t)e * H_DIM * I_DIM + (size_t)(nb * 128) * I_DIM;
  const size_t rowbase = (size_t)g * 128;

  f32x4 acc[4][4] = {};

  const int NK = I_DIM / 64;  // 64
  for (int kt = 0; kt < NK; ++kt) {
    __syncthreads();
#pragma unroll
    for (int it = 0; it < 4; ++it) {
      int id = it * 256 + tid;
      int r = id >> 3;
      int cs = (id & 7) ^ (r & 7);
      lds_load16(inter + (rowbase + r) * (size_t)I_DIM + kt * 64 + cs * 8,
                 smem + id * 16);
      lds_load16(Bbase + (size_t)r * I_DIM + kt * 64 + cs * 8,
                 smem + 16384 + id * 16);
    }
    __syncthreads();
#pragma unroll
    for (int kk = 0; kk < 2; ++kk) {
      bf16x8 af[4], bv[4];
#pragma unroll
      for (int m = 0; m < 4; ++m)
        af[m] = *lds_frag(smem, wr * 64 + m * 16 + l16, kk * 4 + l4);
#pragma unroll
      for (int n = 0; n < 4; ++n)
        bv[n] = *lds_frag(smem + 16384, wn * 64 + n * 16 + l16, kk * 4 + l4);
#pragma unroll
      for (int m = 0; m < 4; ++m)
#pragma unroll
        for (int n = 0; n < 4; ++n)
          acc[m][n] =
              __builtin_amdgcn_mfma_f32_16x16x32_bf16(af[m], bv[n], acc[m][n], 0, 0, 0);
    }
  }

  // ---- epilogue: two 32-row passes through per-wave 8KB LDS slice ----
  __syncthreads();
  float* slice = (float*)(smem + wave * 8192);
  float bias[4];
#pragma unroll
  for (int n = 0; n < 4; ++n)
    bias[n] = b_out[e * H_DIM + nb * 128 + wn * 64 + n * 16 + l16];
#pragma unroll
  for (int p = 0; p < 2; ++p) {
#pragma unroll
    for (int mm = 0; mm < 2; ++mm) {
      int m = p * 2 + mm;
#pragma unroll
      for (int n = 0; n < 4; ++n) {
#pragma unroll
        for (int j = 0; j < 4; ++j) {
          slice[(mm * 16 + l4 * 4 + j) * 64 + n * 16 + l16] =
              acc[m][n][j] + bias[n];
        }
      }
    }
    __syncthreads();  // slice writes visible before cross-lane readback
#pragma unroll
    for (int it = 0; it < 8; ++it) {
      int row = it * 4 + (lane >> 4);      // 0..31
      int col = (lane & 15) * 4;           // 4 floats = 16B
      float4 v = *(const float4*)&slice[row * 64 + col];
      *(float4*)&y[(rowbase + wr * 64 + p * 32 + row) * (size_t)H_DIM +
                   nb * 128 + wn * 64 + col] = v;
    }
    __syncthreads();  // readback done before next pass overwrites slice
  }
}

// ---------------- combine: out[t] = w0*y[slot0] + w1*y[slot1] ---------------
__global__ void __launch_bounds__(256) combine_kernel(
    const float* __restrict__ y, const int* __restrict__ counts,
    const int* __restrict__ se, const float* __restrict__ wtok,
    float* __restrict__ out) {
  const int t = blockIdx.x;
  int poff[NE];
  int run = 0;
#pragma unroll
  for (int e = 0; e < NE; ++e) {
    poff[e] = run;
    run += (counts[e] + 127) & ~127;  // must match 128-row block padding
  }
  int c0 = se[2 * t], c1 = se[2 * t + 1];
  float w0 = wtok[2 * t], w1 = wtok[2 * t + 1];
  const float* y0 = y + (size_t)(poff[c0 >> 20] + (c0 & 0xFFFFF)) * H_DIM;
  const float* y1 = y + (size_t)(poff[c1 >> 20] + (c1 & 0xFFFFF)) * H_DIM;
  int h = threadIdx.x * 4;
  float4 a = *reinterpret_cast<const float4*>(y0 + h);
  float4 b = *reinterpret_cast<const float4*>(y1 + h);
  float4 o;
  o.x = w0 * a.x + w1 * b.x;
  o.y = w0 * a.y + w1 * b.y;
  o.z = w0 * a.z + w1 * b.z;
  o.w = w0 * a.w + w1 * b.w;
  *reinterpret_cast<float4*>(out + (size_t)t * H_DIM + h) = o;
}

extern "C" void kernel_launch(void* const* d_in, const int* in_sizes, int n_in,
                              void* d_out, int out_size, void* d_ws, size_t ws_size,
                              hipStream_t stream) {
  const float* x     = (const float*)d_in[0];
  const float* rw    = (const float*)d_in[1];
  const float* w_in  = (const float*)d_in[2];
  const float* b_in  = (const float*)d_in[3];
  const float* w_out = (const float*)d_in[4];
  const float* b_out = (const float*)d_in[5];
  float* out = (float*)d_out;

  char* ws = (char*)d_ws;
  size_t off = 0;
  auto alloc = [&](size_t bytes) {
    char* p = ws + off;
    off = (off + bytes + 255) & ~(size_t)255;
    return p;
  };
  int* counts            = (int*)alloc(NE * 4);
  int* perm              = (int*)alloc((size_t)NE * CAP * 4);
  int* top2e             = (int*)alloc((size_t)T_TOK * 2 * 4);
  int* se                = (int*)alloc((size_t)T_TOK * 2 * 4);
  float* wtok            = (float*)alloc((size_t)T_TOK * 2 * 4);
  unsigned short* xb     = (unsigned short*)alloc((size_t)T_TOK * H_DIM * 2);
  unsigned short* win_t  = (unsigned short*)alloc((size_t)NE * H_DIM * I_DIM * 2);
  unsigned short* wout_t = (unsigned short*)alloc((size_t)NE * H_DIM * I_DIM * 2);
  unsigned short* inter  = (unsigned short*)alloc((size_t)(T_TOK * 2 + NE * 256) * I_DIM * 2);
  // y overlays ONLY win_t (read-dead after K2's ffn1 part; rewritten by K1's
  // transpose before the next ffn1): need <= 9216*1024*4 = 37.7MB <= 64MB
  float* y = (float*)win_t;
  if (off > ws_size) return;  // ws too small -> visible correctness failure

  prep_kernel<<<T_TOK + NE * 1024, 256, 0, stream>>>(x, rw, top2e, wtok, xb,
                                                     w_in, win_t);
  bucketize_kernel<<<NE, 1024, 0, stream>>>(top2e, counts, perm, se);
  ffn1_wout_kernel<<<32 * RB128 + NE * 1024, 256, 0, stream>>>(
      xb, win_t, b_in, counts, perm, inter, w_out, wout_t);
  ffn2_kernel<<<RB128 * 8, 256, 0, stream>>>(inter, wout_t, b_out, counts, y);
  combine_kernel<<<T_TOK, 256, 0, stream>>>(y, counts, se, wtok, out);
}